// Round 12
// baseline (235.550 us; speedup 1.0000x reference)
//
#include <hip/hip_runtime.h>
#include <hip/hip_bf16.h>
#include <stdint.h>

#define D_IN 1024
#define D_K  128
#define NBATCH 8
#define SEQ  4096
#define MROWS (NBATCH * SEQ)

typedef __attribute__((ext_vector_type(8))) short bf16x8;
typedef __attribute__((ext_vector_type(4))) float f32x4;

__device__ __forceinline__ unsigned short f32_to_bf16(float x) {
    union { float f; uint32_t u; } v; v.f = x;
    uint32_t r = 0x7FFFu + ((v.u >> 16) & 1u);
    return (unsigned short)((v.u + r) >> 16);
}

__device__ __forceinline__ bf16x8 cvt8(float4 lo, float4 hi) {
    bf16x8 r;
    r[0] = (short)f32_to_bf16(lo.x); r[1] = (short)f32_to_bf16(lo.y);
    r[2] = (short)f32_to_bf16(lo.z); r[3] = (short)f32_to_bf16(lo.w);
    r[4] = (short)f32_to_bf16(hi.x); r[5] = (short)f32_to_bf16(hi.y);
    r[6] = (short)f32_to_bf16(hi.z); r[7] = (short)f32_to_bf16(hi.w);
    return r;
}

__device__ __forceinline__ void gload16(const void* src, void* lds) {
    __builtin_amdgcn_global_load_lds(
        (const __attribute__((address_space(1))) void*)src,
        (__attribute__((address_space(3))) void*)lds, 16, 0, 0);
}

// ---------------- W pre-convert (unchanged, passing) ----------------
// Wt[p][kc=0..127][n=0..127] = 8 bf16 of W_p[n][kc*8 .. kc*8+8)  (Wq scaled)
__global__ __launch_bounds__(256)
void wconv_kernel(const float* __restrict__ Wq, const float* __restrict__ Wk,
                  const float* __restrict__ Wv, unsigned short* __restrict__ Wt)
{
    const int t  = blockIdx.x * 256 + threadIdx.x;
    const int n  = t & 127;
    const int kc = (t >> 7) & 127;
    const int p  = t >> 14;
    const float* __restrict__ W = (p == 0) ? Wq : (p == 1) ? Wk : Wv;
    const float sc = (p == 0) ? (1.44269504088896f * 0.0883883476483184f) : 1.0f;
    const float4* src = reinterpret_cast<const float4*>(W + (size_t)n * D_IN + kc * 8);
    float4 a = src[0], b = src[1];
    uint4 o;
    o.x = (uint32_t)f32_to_bf16(a.x * sc) | ((uint32_t)f32_to_bf16(a.y * sc) << 16);
    o.y = (uint32_t)f32_to_bf16(a.z * sc) | ((uint32_t)f32_to_bf16(a.w * sc) << 16);
    o.z = (uint32_t)f32_to_bf16(b.x * sc) | ((uint32_t)f32_to_bf16(b.y * sc) << 16);
    o.w = (uint32_t)f32_to_bf16(b.z * sc) | ((uint32_t)f32_to_bf16(b.w * sc) << 16);
    *reinterpret_cast<uint4*>(Wt + (size_t)t * 8) = o;
}

// ---------------- projection GEMM v12: half-K LDS, 4 blocks/CU ------------
// R11 structure (row-linear stage, barrier-free B-in-regs k-loop) but K is
// processed in two halves so LDS drops 64->32KB: occupancy 2->4 blocks/CU
// (8->16 waves/CU) to hide the loaded-latency that R11 exposed.
#define RBM 32

__global__ __launch_bounds__(256, 4)
void proj_kernel(const float* __restrict__ Xq, const float* __restrict__ Xk,
                 const float* __restrict__ Xv,
                 const unsigned short* __restrict__ Wt,
                 unsigned short* __restrict__ qh, unsigned short* __restrict__ kh,
                 unsigned short* __restrict__ vhT)
{
    const int p = blockIdx.y;
    const float* __restrict__ X = (p == 0) ? Xq : (p == 1) ? Xk : Xv;
    const unsigned short* __restrict__ Wtp = Wt + (size_t)p * 128 * 128 * 8;

    __shared__ unsigned short As[RBM * 512];   // 32KB [row][k-half] bf16, swizzled

    const int tid  = threadIdx.x;
    const int lane = tid & 63;
    const int wave = tid >> 6;
    const int lrow = lane & 15;
    const int g    = lane >> 4;
    const int wr   = (wave >> 1) * 16;
    const int wc   = (wave & 1) * 64;
    const int wbase = blockIdx.x * RBM;

    f32x4 acc[4];
    #pragma unroll
    for (int ni = 0; ni < 4; ++ni) acc[ni] = (f32x4){0.f, 0.f, 0.f, 0.f};

    const int arow = wr + lrow;
    const char* abase = reinterpret_cast<const char*>(As) + arow * 1024;
    const int aswz = (arow & 7) << 4;
    // B entry (kc, n): 16B at Wtp + (kc*128 + n)*8 shorts (R5/R10/R11-proven)
    const unsigned short* __restrict__ wb0 = Wtp + ((size_t)g * 128 + wc + lrow) * 8;

    bf16x8 bb[16];   // B batch: bb[s*4+ni] — all indices static (rule #20)

    #pragma unroll
    for (int kk = 0; kk < 2; ++kk) {
        if (kk) __syncthreads();   // all waves done reading As(kk-1)

        // issue this half's B batch-0 first: latency hides under phase 1
        const unsigned short* __restrict__ wbk = wb0 + (size_t)kk * 64 * 128 * 8;
        #pragma unroll
        for (int s = 0; s < 4; ++s)
            #pragma unroll
            for (int ni = 0; ni < 4; ++ni)
                bb[s * 4 + ni] = *reinterpret_cast<const bf16x8*>(
                    wbk + ((size_t)s * 4 * 128 + ni * 16) * 8);

        // ---- Phase 1: stage 8 row-halves per wave (2KB contiguous each) ----
        {
            const int r0 = wave * 8;
            const char* rowp = reinterpret_cast<const char*>(
                X + (size_t)(wbase + r0) * D_IN + kk * 512) + lane * 32;
            float4 a0 = *reinterpret_cast<const float4*>(rowp);
            float4 a1 = *reinterpret_cast<const float4*>(rowp + 16);
            #pragma unroll
            for (int i = 0; i < 8; ++i) {
                float4 c0 = a0, c1 = a1;
                if (i < 7) {
                    const char* np = rowp + (size_t)(i + 1) * 4096;
                    a0 = *reinterpret_cast<const float4*>(np);
                    a1 = *reinterpret_cast<const float4*>(np + 16);
                }
                const int r = r0 + i;
                *reinterpret_cast<bf16x8*>(reinterpret_cast<char*>(As) + r * 1024 +
                    ((lane * 16) ^ ((r & 7) << 4))) = cvt8(c0, c1);
            }
        }
        __syncthreads();

        // ---- k-loop: 4 batches x 4 k-steps; B in regs, A from LDS ----
        #pragma unroll
        for (int bt = 0; bt < 4; ++bt) {
            #pragma unroll
            for (int s = 0; s < 4; ++s) {
                const int t = bt * 4 + s;          // local k-step 0..15
                bf16x8 af = *reinterpret_cast<const bf16x8*>(
                    abase + ((t * 64 + g * 16) ^ aswz));
                acc[0] = __builtin_amdgcn_mfma_f32_16x16x32_bf16(af, bb[s * 4 + 0], acc[0], 0, 0, 0);
                acc[1] = __builtin_amdgcn_mfma_f32_16x16x32_bf16(af, bb[s * 4 + 1], acc[1], 0, 0, 0);
                acc[2] = __builtin_amdgcn_mfma_f32_16x16x32_bf16(af, bb[s * 4 + 2], acc[2], 0, 0, 0);
                acc[3] = __builtin_amdgcn_mfma_f32_16x16x32_bf16(af, bb[s * 4 + 3], acc[3], 0, 0, 0);
                if (bt < 3) {   // refill slot s for batch bt+1 (WAR-released)
                    const size_t kcb = ((size_t)(bt + 1) * 16 + s * 4) * 128 * 8;
                    #pragma unroll
                    for (int ni = 0; ni < 4; ++ni)
                        bb[s * 4 + ni] = *reinterpret_cast<const bf16x8*>(
                            wbk + kcb + (size_t)ni * 16 * 8);
                }
            }
        }
    }

    // ---- epilogue: col = wc+ni*16+lrow, row = wbase+wr+g*4+r ----
    if (p < 2) {
        unsigned short* __restrict__ Y = (p == 0) ? qh : kh;
        const int rbase = wbase + wr + g * 4;
        #pragma unroll
        for (int ni = 0; ni < 4; ++ni) {
            const int n = wc + ni * 16 + lrow;
            #pragma unroll
            for (int r = 0; r < 4; ++r)
                Y[(size_t)(rbase + r) * D_K + n] = f32_to_bf16(acc[ni][r]);
        }
    } else {
        const int b  = wbase >> 12;
        const int s  = (wbase & 4095) + wr + g * 4;
        #pragma unroll
        for (int ni = 0; ni < 4; ++ni) {
            const int d = wc + ni * 16 + lrow;
            uint2 t;
            t.x = (uint32_t)f32_to_bf16(acc[ni][0]) |
                  ((uint32_t)f32_to_bf16(acc[ni][1]) << 16);
            t.y = (uint32_t)f32_to_bf16(acc[ni][2]) |
                  ((uint32_t)f32_to_bf16(acc[ni][3]) << 16);
            *reinterpret_cast<uint2*>(vhT + ((size_t)(b * D_K + d) << 12) + s) = t;
        }
    }
}

// ---------------- flash attention v10 (R10, passing, ~75us — FROZEN) -------
#define KVB 64

__global__ __launch_bounds__(256, 2)
void attn_kernel(const unsigned short* __restrict__ qh,
                 const unsigned short* __restrict__ kh,
                 const unsigned short* __restrict__ vhT,
                 float* __restrict__ out)
{
    __shared__ unsigned short Ks[2][KVB * D_K];   // 2 x 16KB
    __shared__ unsigned short Vs[2][D_K * KVB];   // 2 x 16KB (V^T)
    __shared__ unsigned short Ps[4][16 * KVB];    // per-wave [16][64]

    const int tid  = threadIdx.x;
    const int lane = tid & 63;
    const int wave = tid >> 6;
    const int b    = blockIdx.x & 7;     // batch -> XCD L2 locality
    const int qt   = blockIdx.x >> 3;
    const int q0   = qt * 64 + wave * 16;
    const int lrow = lane & 15;
    const int g4   = (lane >> 4) << 2;
    const int lk16 = (lane >> 4) * 16;

    const unsigned short* __restrict__ Kb = kh + (size_t)b * SEQ * D_K;
    const unsigned short* __restrict__ Vb = vhT + (size_t)b * D_K * SEQ;
    unsigned short* const Pw = Ps[wave];

    const int kr0  = lane >> 4;
    const int kcbp = (lane & 15) * 16;
    const int vr0  = lane >> 3;
    const int vcbp = (lane & 7) * 16;

    #define STAGE(buf, it_)                                                   \
    do {                                                                      \
        const int s0_ = (it_) * KVB;                                          \
        _Pragma("unroll")                                                     \
        for (int j = 0; j < 4; ++j) {                                         \
            const int blk  = wave * 4 + j;                                    \
            const int krow = blk * 4 + kr0;                                   \
            gload16(reinterpret_cast<const char*>(Kb) +                       \
                        (size_t)(s0_ + krow) * 256 +                          \
                        (kcbp ^ ((krow & 7) << 4)),                           \
                    reinterpret_cast<char*>(Ks[buf]) + blk * 1024);           \
            const int vrow = blk * 8 + vr0;                                   \
            gload16(reinterpret_cast<const char*>(Vb) +                       \
                        (size_t)vrow * (SEQ * 2) + (size_t)s0_ * 2 +          \
                        (vcbp ^ ((vrow & 7) << 4)),                           \
                    reinterpret_cast<char*>(Vs[buf]) + blk * 1024);           \
        }                                                                     \
    } while (0)

    bf16x8 qf[4];
    {
        const char* base = reinterpret_cast<const char*>(
            qh + (size_t)(b * SEQ + q0 + lrow) * D_K);
        #pragma unroll
        for (int ks = 0; ks < 4; ++ks)
            qf[ks] = *reinterpret_cast<const bf16x8*>(base + ks * 64 + lk16);
    }

    f32x4 o[8];
    #pragma unroll
    for (int df = 0; df < 8; ++df) o[df] = (f32x4){0.f, 0.f, 0.f, 0.f};
    float lsum[4] = {0.f, 0.f, 0.f, 0.f};

    STAGE(0, 0);
    asm volatile("s_waitcnt vmcnt(0)" ::: "memory");
    __syncthreads();

    int cur = 0;
    for (int it = 0; it < SEQ / KVB; ++it) {
        if (it + 1 < SEQ / KVB) STAGE(cur ^ 1, it + 1);

        f32x4 sc[4];
        #pragma unroll
        for (int sf = 0; sf < 4; ++sf) sc[sf] = (f32x4){0.f, 0.f, 0.f, 0.f};
        #pragma unroll
        for (int ks = 0; ks < 4; ++ks) {
            #pragma unroll
            for (int sf = 0; sf < 4; ++sf) {
                const int row = sf * 16 + lrow;
                bf16x8 kf = *reinterpret_cast<const bf16x8*>(
                    reinterpret_cast<const char*>(Ks[cur]) + row * 256 +
                    ((ks * 64 + lk16) ^ ((row & 7) << 4)));
                sc[sf] = __builtin_amdgcn_mfma_f32_16x16x32_bf16(qf[ks], kf, sc[sf], 0, 0, 0);
            }
        }

        #pragma unroll
        for (int sf = 0; sf < 4; ++sf) {
            #pragma unroll
            for (int r = 0; r < 4; ++r) {
                float pv = exp2f(sc[sf][r]);
                lsum[r] += pv;
                const int prow = g4 + r;
                const int pcol = (sf * 16 + lrow) * 2;
                *reinterpret_cast<unsigned short*>(
                    reinterpret_cast<char*>(Pw) + prow * 128 +
                    (pcol ^ ((prow & 7) << 4))) = f32_to_bf16(pv);
            }
        }

        #pragma unroll
        for (int ks = 0; ks < 2; ++ks) {
            bf16x8 pf = *reinterpret_cast<const bf16x8*>(
                reinterpret_cast<const char*>(Pw) + lrow * 128 +
                ((ks * 64 + lk16) ^ ((lrow & 7) << 4)));
            #pragma unroll
            for (int df = 0; df < 8; ++df) {
                const int vr = df * 16 + lrow;
                bf16x8 vf = *reinterpret_cast<const bf16x8*>(
                    reinterpret_cast<const char*>(Vs[cur]) + vr * 128 +
                    ((ks * 64 + lk16) ^ ((vr & 7) << 4)));
                o[df] = __builtin_amdgcn_mfma_f32_16x16x32_bf16(pf, vf, o[df], 0, 0, 0);
            }
        }

        asm volatile("s_waitcnt vmcnt(0)" ::: "memory");
        __syncthreads();
        cur ^= 1;
    }
    #undef STAGE

    #pragma unroll
    for (int r = 0; r < 4; ++r) {
        float s = lsum[r];
        s += __shfl_xor(s, 1);
        s += __shfl_xor(s, 2);
        s += __shfl_xor(s, 4);
        s += __shfl_xor(s, 8);
        float inv = 1.0f / s;
        const int row = q0 + g4 + r;
        float* ob = out + (size_t)(b * SEQ + row) * D_K + lrow;
        #pragma unroll
        for (int df = 0; df < 8; ++df)
            ob[df * 16] = o[df][r] * inv;
    }
}

extern "C" void kernel_launch(void* const* d_in, const int* in_sizes, int n_in,
                              void* d_out, int out_size, void* d_ws, size_t ws_size,
                              hipStream_t stream)
{
    (void)in_sizes; (void)n_in; (void)out_size; (void)ws_size;
    const float* q  = (const float*)d_in[0];
    const float* k  = (const float*)d_in[1];
    const float* v  = (const float*)d_in[2];
    const float* Wq = (const float*)d_in[3];
    const float* Wk = (const float*)d_in[4];
    const float* Wv = (const float*)d_in[5];

    unsigned short* qh  = (unsigned short*)d_ws;                 // [32768][128] bf16
    unsigned short* kh  = qh + (size_t)MROWS * D_K;              // [32768][128] bf16
    unsigned short* vhT = kh + (size_t)MROWS * D_K;              // [8][128][4096] bf16
    unsigned short* Wt  = vhT + (size_t)MROWS * D_K;             // [3][128][128][8] bf16

    wconv_kernel<<<dim3(192), 256, 0, stream>>>(Wq, Wk, Wv, Wt);
    proj_kernel<<<dim3(MROWS / RBM, 3), 256, 0, stream>>>(q, k, v, Wt, qh, kh, vhT);
    attn_kernel<<<dim3(NBATCH * (SEQ / 64)), 256, 0, stream>>>(qh, kh, vhT, (float*)d_out);
}

// Round 13
// 222.234 us; speedup vs baseline: 1.0599x; 1.0599x over previous
//
#include <hip/hip_runtime.h>
#include <hip/hip_bf16.h>
#include <stdint.h>

#define D_IN 1024
#define D_K  128
#define NBATCH 8
#define SEQ  4096
#define MROWS (NBATCH * SEQ)

typedef __attribute__((ext_vector_type(8))) short bf16x8;
typedef __attribute__((ext_vector_type(4))) float f32x4;

__device__ __forceinline__ unsigned short f32_to_bf16(float x) {
    union { float f; uint32_t u; } v; v.f = x;
    uint32_t r = 0x7FFFu + ((v.u >> 16) & 1u);
    return (unsigned short)((v.u + r) >> 16);
}

__device__ __forceinline__ bf16x8 cvt8(float4 lo, float4 hi) {
    bf16x8 r;
    r[0] = (short)f32_to_bf16(lo.x); r[1] = (short)f32_to_bf16(lo.y);
    r[2] = (short)f32_to_bf16(lo.z); r[3] = (short)f32_to_bf16(lo.w);
    r[4] = (short)f32_to_bf16(hi.x); r[5] = (short)f32_to_bf16(hi.y);
    r[6] = (short)f32_to_bf16(hi.z); r[7] = (short)f32_to_bf16(hi.w);
    return r;
}

__device__ __forceinline__ void gload16(const void* src, void* lds) {
    __builtin_amdgcn_global_load_lds(
        (const __attribute__((address_space(1))) void*)src,
        (__attribute__((address_space(3))) void*)lds, 16, 0, 0);
}

// ---------------- W pre-convert (unchanged, passing) ----------------
// Wt[p][kc=0..127][n=0..127] = 8 bf16 of W_p[n][kc*8 .. kc*8+8)  (Wq scaled)
__global__ __launch_bounds__(256)
void wconv_kernel(const float* __restrict__ Wq, const float* __restrict__ Wk,
                  const float* __restrict__ Wv, unsigned short* __restrict__ Wt)
{
    const int t  = blockIdx.x * 256 + threadIdx.x;
    const int n  = t & 127;
    const int kc = (t >> 7) & 127;
    const int p  = t >> 14;
    const float* __restrict__ W = (p == 0) ? Wq : (p == 1) ? Wk : Wv;
    const float sc = (p == 0) ? (1.44269504088896f * 0.0883883476483184f) : 1.0f;
    const float4* src = reinterpret_cast<const float4*>(W + (size_t)n * D_IN + kc * 8);
    float4 a = src[0], b = src[1];
    uint4 o;
    o.x = (uint32_t)f32_to_bf16(a.x * sc) | ((uint32_t)f32_to_bf16(a.y * sc) << 16);
    o.y = (uint32_t)f32_to_bf16(a.z * sc) | ((uint32_t)f32_to_bf16(a.w * sc) << 16);
    o.z = (uint32_t)f32_to_bf16(b.x * sc) | ((uint32_t)f32_to_bf16(b.y * sc) << 16);
    o.w = (uint32_t)f32_to_bf16(b.z * sc) | ((uint32_t)f32_to_bf16(b.w * sc) << 16);
    *reinterpret_cast<uint4*>(Wt + (size_t)t * 8) = o;
}

// ---------------- projection GEMM v13: full-density X loads ----------------
// Every X load instruction is 64 lanes x 16B CONTIGUOUS (1KB, 16 cache lines)
// -- the m13-copy / diag_stream pattern. fp32 staged to LDS in quarter-K
// tiles [32][256] (32KB); cvt->bf16 at fragment-read time. B path (bb[16]
// register batches from L2-hot Wt) and epilogue are R11/R12-proven.
#define RBM 32

__global__ __launch_bounds__(256, 3)
void proj_kernel(const float* __restrict__ Xq, const float* __restrict__ Xk,
                 const float* __restrict__ Xv,
                 const unsigned short* __restrict__ Wt,
                 unsigned short* __restrict__ qh, unsigned short* __restrict__ kh,
                 unsigned short* __restrict__ vhT)
{
    const int p = blockIdx.y;
    const float* __restrict__ X = (p == 0) ? Xq : (p == 1) ? Xk : Xv;
    const unsigned short* __restrict__ Wtp = Wt + (size_t)p * 128 * 128 * 8;

    __shared__ float Asf[RBM * 256];   // 32KB [row][256 f32], 32B-XOR swizzled

    const int tid  = threadIdx.x;
    const int lane = tid & 63;
    const int wave = tid >> 6;
    const int lrow = lane & 15;
    const int g    = lane >> 4;
    const int wr   = (wave >> 1) * 16;
    const int wc   = (wave & 1) * 64;
    const int wbase = blockIdx.x * RBM;

    f32x4 acc[4];
    #pragma unroll
    for (int ni = 0; ni < 4; ++ni) acc[ni] = (f32x4){0.f, 0.f, 0.f, 0.f};

    const int arow = wr + lrow;
    char* const abase = reinterpret_cast<char*>(Asf) + arow * 1024;
    const int aswz = (arow & 7) << 5;
    bf16x8 bb[16];   // bb[s*4+ni] — all indices static (rule #20)

    #pragma unroll
    for (int kk = 0; kk < 4; ++kk) {   // quarter-K: floats [kk*256, kk*256+256)
        if (kk) __syncthreads();       // all waves done reading Asf(kk-1)

        // B batch-0 for this quarter (kc = kk*32 + t*4 + g, t = bt*4+s)
        const unsigned short* __restrict__ wbk =
            Wtp + ((size_t)(kk * 32 + g) * 128 + wc + lrow) * 8;
        #pragma unroll
        for (int s = 0; s < 4; ++s)
            #pragma unroll
            for (int ni = 0; ni < 4; ++ni)
                bb[s * 4 + ni] = *reinterpret_cast<const bf16x8*>(
                    wbk + ((size_t)(s * 4) * 128 + ni * 16) * 8);

        // ---- stage: 8 rows/wave, ONE contiguous-1KB float4 load per row ----
        {
            const int r0 = wave * 8;
            const char* src = reinterpret_cast<const char*>(
                X + (size_t)(wbase + r0) * D_IN + kk * 256) + lane * 16;
            float4 L0 = *reinterpret_cast<const float4*>(src);
            float4 L1 = *reinterpret_cast<const float4*>(src + 1 * 4096);
            float4 L2 = *reinterpret_cast<const float4*>(src + 2 * 4096);
            float4 L3 = *reinterpret_cast<const float4*>(src + 3 * 4096);
            float4 L4 = *reinterpret_cast<const float4*>(src + 4 * 4096);
            float4 L5 = *reinterpret_cast<const float4*>(src + 5 * 4096);
            float4 L6 = *reinterpret_cast<const float4*>(src + 6 * 4096);
            float4 L7 = *reinterpret_cast<const float4*>(src + 7 * 4096);
            char* const dst = reinterpret_cast<char*>(Asf);
            const int lb = lane * 16;
            #define WR(i, Li)                                                  \
            do {                                                               \
                const int r_ = r0 + (i);                                       \
                *reinterpret_cast<float4*>(dst + r_ * 1024 +                   \
                    (lb ^ ((r_ & 7) << 5))) = Li;                              \
            } while (0)
            WR(0, L0); WR(1, L1); WR(2, L2); WR(3, L3);
            WR(4, L4); WR(5, L5); WR(6, L6); WR(7, L7);
            #undef WR
        }
        __syncthreads();

        // ---- kloop: 2 batches x 4 k-steps; A from fp32 LDS (cvt at read) ----
        #pragma unroll
        for (int bt = 0; bt < 2; ++bt) {
            #pragma unroll
            for (int s = 0; s < 4; ++s) {
                const int t = bt * 4 + s;               // local k-step 0..7
                const int boff = (t * 128 + g * 32) ^ aswz;   // bit4-free base
                float4 lo = *reinterpret_cast<const float4*>(abase + boff);
                float4 hi = *reinterpret_cast<const float4*>(abase + boff + 16);
                bf16x8 af = cvt8(lo, hi);
                acc[0] = __builtin_amdgcn_mfma_f32_16x16x32_bf16(af, bb[s * 4 + 0], acc[0], 0, 0, 0);
                acc[1] = __builtin_amdgcn_mfma_f32_16x16x32_bf16(af, bb[s * 4 + 1], acc[1], 0, 0, 0);
                acc[2] = __builtin_amdgcn_mfma_f32_16x16x32_bf16(af, bb[s * 4 + 2], acc[2], 0, 0, 0);
                acc[3] = __builtin_amdgcn_mfma_f32_16x16x32_bf16(af, bb[s * 4 + 3], acc[3], 0, 0, 0);
                if (bt == 0) {   // refill slot s for k-steps 4..7 (WAR-released)
                    #pragma unroll
                    for (int ni = 0; ni < 4; ++ni)
                        bb[s * 4 + ni] = *reinterpret_cast<const bf16x8*>(
                            wbk + ((size_t)(16 + s * 4) * 128 + ni * 16) * 8);
                }
            }
        }
    }

    // ---- epilogue (R11/R12-proven): col = wc+ni*16+lrow, row = wbase+wr+g*4+r
    if (p < 2) {
        unsigned short* __restrict__ Y = (p == 0) ? qh : kh;
        const int rbase = wbase + wr + g * 4;
        #pragma unroll
        for (int ni = 0; ni < 4; ++ni) {
            const int n = wc + ni * 16 + lrow;
            #pragma unroll
            for (int r = 0; r < 4; ++r)
                Y[(size_t)(rbase + r) * D_K + n] = f32_to_bf16(acc[ni][r]);
        }
    } else {
        const int b  = wbase >> 12;
        const int s  = (wbase & 4095) + wr + g * 4;
        #pragma unroll
        for (int ni = 0; ni < 4; ++ni) {
            const int d = wc + ni * 16 + lrow;
            uint2 t;
            t.x = (uint32_t)f32_to_bf16(acc[ni][0]) |
                  ((uint32_t)f32_to_bf16(acc[ni][1]) << 16);
            t.y = (uint32_t)f32_to_bf16(acc[ni][2]) |
                  ((uint32_t)f32_to_bf16(acc[ni][3]) << 16);
            *reinterpret_cast<uint2*>(vhT + ((size_t)(b * D_K + d) << 12) + s) = t;
        }
    }
}

// ---------------- flash attention v10 (R10, passing, ~75us — FROZEN) -------
#define KVB 64

__global__ __launch_bounds__(256, 2)
void attn_kernel(const unsigned short* __restrict__ qh,
                 const unsigned short* __restrict__ kh,
                 const unsigned short* __restrict__ vhT,
                 float* __restrict__ out)
{
    __shared__ unsigned short Ks[2][KVB * D_K];   // 2 x 16KB
    __shared__ unsigned short Vs[2][D_K * KVB];   // 2 x 16KB (V^T)
    __shared__ unsigned short Ps[4][16 * KVB];    // per-wave [16][64]

    const int tid  = threadIdx.x;
    const int lane = tid & 63;
    const int wave = tid >> 6;
    const int b    = blockIdx.x & 7;     // batch -> XCD L2 locality
    const int qt   = blockIdx.x >> 3;
    const int q0   = qt * 64 + wave * 16;
    const int lrow = lane & 15;
    const int g4   = (lane >> 4) << 2;
    const int lk16 = (lane >> 4) * 16;

    const unsigned short* __restrict__ Kb = kh + (size_t)b * SEQ * D_K;
    const unsigned short* __restrict__ Vb = vhT + (size_t)b * D_K * SEQ;
    unsigned short* const Pw = Ps[wave];

    const int kr0  = lane >> 4;
    const int kcbp = (lane & 15) * 16;
    const int vr0  = lane >> 3;
    const int vcbp = (lane & 7) * 16;

    #define STAGE(buf, it_)                                                   \
    do {                                                                      \
        const int s0_ = (it_) * KVB;                                          \
        _Pragma("unroll")                                                     \
        for (int j = 0; j < 4; ++j) {                                         \
            const int blk  = wave * 4 + j;                                    \
            const int krow = blk * 4 + kr0;                                   \
            gload16(reinterpret_cast<const char*>(Kb) +                       \
                        (size_t)(s0_ + krow) * 256 +                          \
                        (kcbp ^ ((krow & 7) << 4)),                           \
                    reinterpret_cast<char*>(Ks[buf]) + blk * 1024);           \
            const int vrow = blk * 8 + vr0;                                   \
            gload16(reinterpret_cast<const char*>(Vb) +                       \
                        (size_t)vrow * (SEQ * 2) + (size_t)s0_ * 2 +          \
                        (vcbp ^ ((vrow & 7) << 4)),                           \
                    reinterpret_cast<char*>(Vs[buf]) + blk * 1024);           \
        }                                                                     \
    } while (0)

    bf16x8 qf[4];
    {
        const char* base = reinterpret_cast<const char*>(
            qh + (size_t)(b * SEQ + q0 + lrow) * D_K);
        #pragma unroll
        for (int ks = 0; ks < 4; ++ks)
            qf[ks] = *reinterpret_cast<const bf16x8*>(base + ks * 64 + lk16);
    }

    f32x4 o[8];
    #pragma unroll
    for (int df = 0; df < 8; ++df) o[df] = (f32x4){0.f, 0.f, 0.f, 0.f};
    float lsum[4] = {0.f, 0.f, 0.f, 0.f};

    STAGE(0, 0);
    asm volatile("s_waitcnt vmcnt(0)" ::: "memory");
    __syncthreads();

    int cur = 0;
    for (int it = 0; it < SEQ / KVB; ++it) {
        if (it + 1 < SEQ / KVB) STAGE(cur ^ 1, it + 1);

        f32x4 sc[4];
        #pragma unroll
        for (int sf = 0; sf < 4; ++sf) sc[sf] = (f32x4){0.f, 0.f, 0.f, 0.f};
        #pragma unroll
        for (int ks = 0; ks < 4; ++ks) {
            #pragma unroll
            for (int sf = 0; sf < 4; ++sf) {
                const int row = sf * 16 + lrow;
                bf16x8 kf = *reinterpret_cast<const bf16x8*>(
                    reinterpret_cast<const char*>(Ks[cur]) + row * 256 +
                    ((ks * 64 + lk16) ^ ((row & 7) << 4)));
                sc[sf] = __builtin_amdgcn_mfma_f32_16x16x32_bf16(qf[ks], kf, sc[sf], 0, 0, 0);
            }
        }

        #pragma unroll
        for (int sf = 0; sf < 4; ++sf) {
            #pragma unroll
            for (int r = 0; r < 4; ++r) {
                float pv = exp2f(sc[sf][r]);
                lsum[r] += pv;
                const int prow = g4 + r;
                const int pcol = (sf * 16 + lrow) * 2;
                *reinterpret_cast<unsigned short*>(
                    reinterpret_cast<char*>(Pw) + prow * 128 +
                    (pcol ^ ((prow & 7) << 4))) = f32_to_bf16(pv);
            }
        }

        #pragma unroll
        for (int ks = 0; ks < 2; ++ks) {
            bf16x8 pf = *reinterpret_cast<const bf16x8*>(
                reinterpret_cast<const char*>(Pw) + lrow * 128 +
                ((ks * 64 + lk16) ^ ((lrow & 7) << 4)));
            #pragma unroll
            for (int df = 0; df < 8; ++df) {
                const int vr = df * 16 + lrow;
                bf16x8 vf = *reinterpret_cast<const bf16x8*>(
                    reinterpret_cast<const char*>(Vs[cur]) + vr * 128 +
                    ((ks * 64 + lk16) ^ ((vr & 7) << 4)));
                o[df] = __builtin_amdgcn_mfma_f32_16x16x32_bf16(pf, vf, o[df], 0, 0, 0);
            }
        }

        asm volatile("s_waitcnt vmcnt(0)" ::: "memory");
        __syncthreads();
        cur ^= 1;
    }
    #undef STAGE

    #pragma unroll
    for (int r = 0; r < 4; ++r) {
        float s = lsum[r];
        s += __shfl_xor(s, 1);
        s += __shfl_xor(s, 2);
        s += __shfl_xor(s, 4);
        s += __shfl_xor(s, 8);
        float inv = 1.0f / s;
        const int row = q0 + g4 + r;
        float* ob = out + (size_t)(b * SEQ + row) * D_K + lrow;
        #pragma unroll
        for (int df = 0; df < 8; ++df)
            ob[df * 16] = o[df][r] * inv;
    }
}

extern "C" void kernel_launch(void* const* d_in, const int* in_sizes, int n_in,
                              void* d_out, int out_size, void* d_ws, size_t ws_size,
                              hipStream_t stream)
{
    (void)in_sizes; (void)n_in; (void)out_size; (void)ws_size;
    const float* q  = (const float*)d_in[0];
    const float* k  = (const float*)d_in[1];
    const float* v  = (const float*)d_in[2];
    const float* Wq = (const float*)d_in[3];
    const float* Wk = (const float*)d_in[4];
    const float* Wv = (const float*)d_in[5];

    unsigned short* qh  = (unsigned short*)d_ws;                 // [32768][128] bf16
    unsigned short* kh  = qh + (size_t)MROWS * D_K;              // [32768][128] bf16
    unsigned short* vhT = kh + (size_t)MROWS * D_K;              // [8][128][4096] bf16
    unsigned short* Wt  = vhT + (size_t)MROWS * D_K;             // [3][128][128][8] bf16

    wconv_kernel<<<dim3(192), 256, 0, stream>>>(Wq, Wk, Wv, Wt);
    proj_kernel<<<dim3(MROWS / RBM, 3), 256, 0, stream>>>(q, k, v, Wt, qh, kh, vhT);
    attn_kernel<<<dim3(NBATCH * (SEQ / 64)), 256, 0, stream>>>(qh, kh, vhT, (float*)d_out);
}

// Round 14
// 211.423 us; speedup vs baseline: 1.1141x; 1.0511x over previous
//
#include <hip/hip_runtime.h>
#include <hip/hip_bf16.h>
#include <stdint.h>

#define D_IN 1024
#define D_K  128
#define NBATCH 8
#define SEQ  4096
#define MROWS (NBATCH * SEQ)

typedef __attribute__((ext_vector_type(8))) short bf16x8;
typedef __attribute__((ext_vector_type(4))) float f32x4;

__device__ __forceinline__ unsigned short f32_to_bf16(float x) {
    union { float f; uint32_t u; } v; v.f = x;
    uint32_t r = 0x7FFFu + ((v.u >> 16) & 1u);
    return (unsigned short)((v.u + r) >> 16);
}

__device__ __forceinline__ bf16x8 cvt8(float4 lo, float4 hi) {
    bf16x8 r;
    r[0] = (short)f32_to_bf16(lo.x); r[1] = (short)f32_to_bf16(lo.y);
    r[2] = (short)f32_to_bf16(lo.z); r[3] = (short)f32_to_bf16(lo.w);
    r[4] = (short)f32_to_bf16(hi.x); r[5] = (short)f32_to_bf16(hi.y);
    r[6] = (short)f32_to_bf16(hi.z); r[7] = (short)f32_to_bf16(hi.w);
    return r;
}

__device__ __forceinline__ void gload16(const void* src, void* lds) {
    __builtin_amdgcn_global_load_lds(
        (const __attribute__((address_space(1))) void*)src,
        (__attribute__((address_space(3))) void*)lds, 16, 0, 0);
}

// ---------------- W pre-convert (unchanged, passing) ----------------
// Wt[p][kc=0..127][n=0..127] = 8 bf16 of W_p[n][kc*8 .. kc*8+8)  (Wq scaled)
__global__ __launch_bounds__(256)
void wconv_kernel(const float* __restrict__ Wq, const float* __restrict__ Wk,
                  const float* __restrict__ Wv, unsigned short* __restrict__ Wt)
{
    const int t  = blockIdx.x * 256 + threadIdx.x;
    const int n  = t & 127;
    const int kc = (t >> 7) & 127;
    const int p  = t >> 14;
    const float* __restrict__ W = (p == 0) ? Wq : (p == 1) ? Wk : Wv;
    const float sc = (p == 0) ? (1.44269504088896f * 0.0883883476483184f) : 1.0f;
    const float4* src = reinterpret_cast<const float4*>(W + (size_t)n * D_IN + kc * 8);
    float4 a = src[0], b = src[1];
    uint4 o;
    o.x = (uint32_t)f32_to_bf16(a.x * sc) | ((uint32_t)f32_to_bf16(a.y * sc) << 16);
    o.y = (uint32_t)f32_to_bf16(a.z * sc) | ((uint32_t)f32_to_bf16(a.w * sc) << 16);
    o.z = (uint32_t)f32_to_bf16(b.x * sc) | ((uint32_t)f32_to_bf16(b.y * sc) << 16);
    o.w = (uint32_t)f32_to_bf16(b.z * sc) | ((uint32_t)f32_to_bf16(b.w * sc) << 16);
    *reinterpret_cast<uint4*>(Wt + (size_t)t * 8) = o;
}

// ---------------- projection GEMM v14: column-split waves ------------------
// v13's full-density X staging kept; wave decomposition changed to
// 32 rows x 32 cols per wave -> B fragments disjoint across waves:
// B traffic/block 512KB -> 256KB and the bb dependence chain halves.
#define RBM 32

__global__ __launch_bounds__(256, 3)
void proj_kernel(const float* __restrict__ Xq, const float* __restrict__ Xk,
                 const float* __restrict__ Xv,
                 const unsigned short* __restrict__ Wt,
                 unsigned short* __restrict__ qh, unsigned short* __restrict__ kh,
                 unsigned short* __restrict__ vhT)
{
    const int p = blockIdx.y;
    const float* __restrict__ X = (p == 0) ? Xq : (p == 1) ? Xk : Xv;
    const unsigned short* __restrict__ Wtp = Wt + (size_t)p * 128 * 128 * 8;

    __shared__ float Asf[RBM * 256];   // 32KB [row][256 f32], 32B-XOR swizzled

    const int tid  = threadIdx.x;
    const int lane = tid & 63;
    const int w    = tid >> 6;           // wave = column group (32 cols)
    const int lrow = lane & 15;
    const int g    = lane >> 4;
    const int wbase = blockIdx.x * RBM;

    f32x4 acc[2][2];
    #pragma unroll
    for (int mi = 0; mi < 2; ++mi)
        #pragma unroll
        for (int ni = 0; ni < 2; ++ni)
            acc[mi][ni] = (f32x4){0.f, 0.f, 0.f, 0.f};

    char* const abase0 = reinterpret_cast<char*>(Asf) + lrow * 1024;        // rows 0..15
    char* const abase1 = reinterpret_cast<char*>(Asf) + (16 + lrow) * 1024; // rows 16..31
    const int aswz = (lrow & 7) << 5;    // (16+lrow)&7 == lrow&7: same swizzle
    bf16x8 bb[8];    // bb[s*2+ni] — all indices static (rule #20)

    #pragma unroll
    for (int kk = 0; kk < 4; ++kk) {   // quarter-K: floats [kk*256, kk*256+256)
        if (kk) __syncthreads();       // all waves done reading Asf(kk-1)

        // B batch-0 for this quarter (kc = kk*32 + t*4 + g; n = w*32+ni*16+lrow)
        const unsigned short* __restrict__ wbk =
            Wtp + ((size_t)(kk * 32 + g) * 128 + w * 32 + lrow) * 8;
        #pragma unroll
        for (int s = 0; s < 4; ++s)
            #pragma unroll
            for (int ni = 0; ni < 2; ++ni)
                bb[s * 2 + ni] = *reinterpret_cast<const bf16x8*>(
                    wbk + ((size_t)(s * 4) * 128 + ni * 16) * 8);

        // ---- stage: 8 rows/wave, ONE contiguous-1KB float4 load per row ----
        {
            const int r0 = w * 8;
            const char* src = reinterpret_cast<const char*>(
                X + (size_t)(wbase + r0) * D_IN + kk * 256) + lane * 16;
            float4 L0 = *reinterpret_cast<const float4*>(src);
            float4 L1 = *reinterpret_cast<const float4*>(src + 1 * 4096);
            float4 L2 = *reinterpret_cast<const float4*>(src + 2 * 4096);
            float4 L3 = *reinterpret_cast<const float4*>(src + 3 * 4096);
            float4 L4 = *reinterpret_cast<const float4*>(src + 4 * 4096);
            float4 L5 = *reinterpret_cast<const float4*>(src + 5 * 4096);
            float4 L6 = *reinterpret_cast<const float4*>(src + 6 * 4096);
            float4 L7 = *reinterpret_cast<const float4*>(src + 7 * 4096);
            char* const dst = reinterpret_cast<char*>(Asf);
            const int lb = lane * 16;
            #define WR(i, Li)                                                  \
            do {                                                               \
                const int r_ = r0 + (i);                                       \
                *reinterpret_cast<float4*>(dst + r_ * 1024 +                   \
                    (lb ^ ((r_ & 7) << 5))) = Li;                              \
            } while (0)
            WR(0, L0); WR(1, L1); WR(2, L2); WR(3, L3);
            WR(4, L4); WR(5, L5); WR(6, L6); WR(7, L7);
            #undef WR
        }
        __syncthreads();

        // ---- kloop: 2 batches x 4 k-steps; 2 A-frags + 2 B-frags, 4 MFMA ----
        #pragma unroll
        for (int bt = 0; bt < 2; ++bt) {
            #pragma unroll
            for (int s = 0; s < 4; ++s) {
                const int t = bt * 4 + s;                     // local k-step 0..7
                const int boff = (t * 128 + g * 32) ^ aswz;
                float4 lo0 = *reinterpret_cast<const float4*>(abase0 + boff);
                float4 hi0 = *reinterpret_cast<const float4*>(abase0 + boff + 16);
                float4 lo1 = *reinterpret_cast<const float4*>(abase1 + boff);
                float4 hi1 = *reinterpret_cast<const float4*>(abase1 + boff + 16);
                bf16x8 af0 = cvt8(lo0, hi0);
                bf16x8 af1 = cvt8(lo1, hi1);
                acc[0][0] = __builtin_amdgcn_mfma_f32_16x16x32_bf16(af0, bb[s * 2 + 0], acc[0][0], 0, 0, 0);
                acc[0][1] = __builtin_amdgcn_mfma_f32_16x16x32_bf16(af0, bb[s * 2 + 1], acc[0][1], 0, 0, 0);
                acc[1][0] = __builtin_amdgcn_mfma_f32_16x16x32_bf16(af1, bb[s * 2 + 0], acc[1][0], 0, 0, 0);
                acc[1][1] = __builtin_amdgcn_mfma_f32_16x16x32_bf16(af1, bb[s * 2 + 1], acc[1][1], 0, 0, 0);
                if (bt == 0) {   // refill slot s for k-steps 4..7 (WAR-released)
                    #pragma unroll
                    for (int ni = 0; ni < 2; ++ni)
                        bb[s * 2 + ni] = *reinterpret_cast<const bf16x8*>(
                            wbk + ((size_t)(16 + s * 4) * 128 + ni * 16) * 8);
                }
            }
        }
    }

    // ---- epilogue: col = w*32+ni*16+lrow, row = wbase + mi*16 + g*4 + r ----
    if (p < 2) {
        unsigned short* __restrict__ Y = (p == 0) ? qh : kh;
        #pragma unroll
        for (int mi = 0; mi < 2; ++mi) {
            const int rbase = wbase + mi * 16 + g * 4;
            #pragma unroll
            for (int ni = 0; ni < 2; ++ni) {
                const int n = w * 32 + ni * 16 + lrow;
                #pragma unroll
                for (int r = 0; r < 4; ++r)
                    Y[(size_t)(rbase + r) * D_K + n] = f32_to_bf16(acc[mi][ni][r]);
            }
        }
    } else {
        const int b = wbase >> 12;
        #pragma unroll
        for (int mi = 0; mi < 2; ++mi) {
            const int s = (wbase & 4095) + mi * 16 + g * 4;
            #pragma unroll
            for (int ni = 0; ni < 2; ++ni) {
                const int d = w * 32 + ni * 16 + lrow;
                uint2 t;
                t.x = (uint32_t)f32_to_bf16(acc[mi][ni][0]) |
                      ((uint32_t)f32_to_bf16(acc[mi][ni][1]) << 16);
                t.y = (uint32_t)f32_to_bf16(acc[mi][ni][2]) |
                      ((uint32_t)f32_to_bf16(acc[mi][ni][3]) << 16);
                *reinterpret_cast<uint2*>(vhT + ((size_t)(b * D_K + d) << 12) + s) = t;
            }
        }
    }
}

// ---------------- flash attention v10 (R10, passing, ~75us — FROZEN) -------
#define KVB 64

__global__ __launch_bounds__(256, 2)
void attn_kernel(const unsigned short* __restrict__ qh,
                 const unsigned short* __restrict__ kh,
                 const unsigned short* __restrict__ vhT,
                 float* __restrict__ out)
{
    __shared__ unsigned short Ks[2][KVB * D_K];   // 2 x 16KB
    __shared__ unsigned short Vs[2][D_K * KVB];   // 2 x 16KB (V^T)
    __shared__ unsigned short Ps[4][16 * KVB];    // per-wave [16][64]

    const int tid  = threadIdx.x;
    const int lane = tid & 63;
    const int wave = tid >> 6;
    const int b    = blockIdx.x & 7;     // batch -> XCD L2 locality
    const int qt   = blockIdx.x >> 3;
    const int q0   = qt * 64 + wave * 16;
    const int lrow = lane & 15;
    const int g4   = (lane >> 4) << 2;
    const int lk16 = (lane >> 4) * 16;

    const unsigned short* __restrict__ Kb = kh + (size_t)b * SEQ * D_K;
    const unsigned short* __restrict__ Vb = vhT + (size_t)b * D_K * SEQ;
    unsigned short* const Pw = Ps[wave];

    const int kr0  = lane >> 4;
    const int kcbp = (lane & 15) * 16;
    const int vr0  = lane >> 3;
    const int vcbp = (lane & 7) * 16;

    #define STAGE(buf, it_)                                                   \
    do {                                                                      \
        const int s0_ = (it_) * KVB;                                          \
        _Pragma("unroll")                                                     \
        for (int j = 0; j < 4; ++j) {                                         \
            const int blk  = wave * 4 + j;                                    \
            const int krow = blk * 4 + kr0;                                   \
            gload16(reinterpret_cast<const char*>(Kb) +                       \
                        (size_t)(s0_ + krow) * 256 +                          \
                        (kcbp ^ ((krow & 7) << 4)),                           \
                    reinterpret_cast<char*>(Ks[buf]) + blk * 1024);           \
            const int vrow = blk * 8 + vr0;                                   \
            gload16(reinterpret_cast<const char*>(Vb) +                       \
                        (size_t)vrow * (SEQ * 2) + (size_t)s0_ * 2 +          \
                        (vcbp ^ ((vrow & 7) << 4)),                           \
                    reinterpret_cast<char*>(Vs[buf]) + blk * 1024);           \
        }                                                                     \
    } while (0)

    bf16x8 qf[4];
    {
        const char* base = reinterpret_cast<const char*>(
            qh + (size_t)(b * SEQ + q0 + lrow) * D_K);
        #pragma unroll
        for (int ks = 0; ks < 4; ++ks)
            qf[ks] = *reinterpret_cast<const bf16x8*>(base + ks * 64 + lk16);
    }

    f32x4 o[8];
    #pragma unroll
    for (int df = 0; df < 8; ++df) o[df] = (f32x4){0.f, 0.f, 0.f, 0.f};
    float lsum[4] = {0.f, 0.f, 0.f, 0.f};

    STAGE(0, 0);
    asm volatile("s_waitcnt vmcnt(0)" ::: "memory");
    __syncthreads();

    int cur = 0;
    for (int it = 0; it < SEQ / KVB; ++it) {
        if (it + 1 < SEQ / KVB) STAGE(cur ^ 1, it + 1);

        f32x4 sc[4];
        #pragma unroll
        for (int sf = 0; sf < 4; ++sf) sc[sf] = (f32x4){0.f, 0.f, 0.f, 0.f};
        #pragma unroll
        for (int ks = 0; ks < 4; ++ks) {
            #pragma unroll
            for (int sf = 0; sf < 4; ++sf) {
                const int row = sf * 16 + lrow;
                bf16x8 kf = *reinterpret_cast<const bf16x8*>(
                    reinterpret_cast<const char*>(Ks[cur]) + row * 256 +
                    ((ks * 64 + lk16) ^ ((row & 7) << 4)));
                sc[sf] = __builtin_amdgcn_mfma_f32_16x16x32_bf16(qf[ks], kf, sc[sf], 0, 0, 0);
            }
        }

        #pragma unroll
        for (int sf = 0; sf < 4; ++sf) {
            #pragma unroll
            for (int r = 0; r < 4; ++r) {
                float pv = exp2f(sc[sf][r]);
                lsum[r] += pv;
                const int prow = g4 + r;
                const int pcol = (sf * 16 + lrow) * 2;
                *reinterpret_cast<unsigned short*>(
                    reinterpret_cast<char*>(Pw) + prow * 128 +
                    (pcol ^ ((prow & 7) << 4))) = f32_to_bf16(pv);
            }
        }

        #pragma unroll
        for (int ks = 0; ks < 2; ++ks) {
            bf16x8 pf = *reinterpret_cast<const bf16x8*>(
                reinterpret_cast<const char*>(Pw) + lrow * 128 +
                ((ks * 64 + lk16) ^ ((lrow & 7) << 4)));
            #pragma unroll
            for (int df = 0; df < 8; ++df) {
                const int vr = df * 16 + lrow;
                bf16x8 vf = *reinterpret_cast<const bf16x8*>(
                    reinterpret_cast<const char*>(Vs[cur]) + vr * 128 +
                    ((ks * 64 + lk16) ^ ((vr & 7) << 4)));
                o[df] = __builtin_amdgcn_mfma_f32_16x16x32_bf16(pf, vf, o[df], 0, 0, 0);
            }
        }

        asm volatile("s_waitcnt vmcnt(0)" ::: "memory");
        __syncthreads();
        cur ^= 1;
    }
    #undef STAGE

    #pragma unroll
    for (int r = 0; r < 4; ++r) {
        float s = lsum[r];
        s += __shfl_xor(s, 1);
        s += __shfl_xor(s, 2);
        s += __shfl_xor(s, 4);
        s += __shfl_xor(s, 8);
        float inv = 1.0f / s;
        const int row = q0 + g4 + r;
        float* ob = out + (size_t)(b * SEQ + row) * D_K + lrow;
        #pragma unroll
        for (int df = 0; df < 8; ++df)
            ob[df * 16] = o[df][r] * inv;
    }
}

extern "C" void kernel_launch(void* const* d_in, const int* in_sizes, int n_in,
                              void* d_out, int out_size, void* d_ws, size_t ws_size,
                              hipStream_t stream)
{
    (void)in_sizes; (void)n_in; (void)out_size; (void)ws_size;
    const float* q  = (const float*)d_in[0];
    const float* k  = (const float*)d_in[1];
    const float* v  = (const float*)d_in[2];
    const float* Wq = (const float*)d_in[3];
    const float* Wk = (const float*)d_in[4];
    const float* Wv = (const float*)d_in[5];

    unsigned short* qh  = (unsigned short*)d_ws;                 // [32768][128] bf16
    unsigned short* kh  = qh + (size_t)MROWS * D_K;              // [32768][128] bf16
    unsigned short* vhT = kh + (size_t)MROWS * D_K;              // [8][128][4096] bf16
    unsigned short* Wt  = vhT + (size_t)MROWS * D_K;             // [3][128][128][8] bf16

    wconv_kernel<<<dim3(192), 256, 0, stream>>>(Wq, Wk, Wv, Wt);
    proj_kernel<<<dim3(MROWS / RBM, 3), 256, 0, stream>>>(q, k, v, Wt, qh, kh, vhT);
    attn_kernel<<<dim3(NBATCH * (SEQ / 64)), 256, 0, stream>>>(qh, kh, vhT, (float*)d_out);
}

// Round 15
// 204.964 us; speedup vs baseline: 1.1492x; 1.0315x over previous
//
#include <hip/hip_runtime.h>
#include <hip/hip_bf16.h>
#include <stdint.h>

#define D_IN 1024
#define D_K  128
#define NBATCH 8
#define SEQ  4096
#define MROWS (NBATCH * SEQ)

typedef __attribute__((ext_vector_type(8))) short bf16x8;
typedef __attribute__((ext_vector_type(4))) float f32x4;

__device__ __forceinline__ unsigned short f32_to_bf16(float x) {
    union { float f; uint32_t u; } v; v.f = x;
    uint32_t r = 0x7FFFu + ((v.u >> 16) & 1u);
    return (unsigned short)((v.u + r) >> 16);
}

__device__ __forceinline__ bf16x8 cvt8(float4 lo, float4 hi) {
    bf16x8 r;
    r[0] = (short)f32_to_bf16(lo.x); r[1] = (short)f32_to_bf16(lo.y);
    r[2] = (short)f32_to_bf16(lo.z); r[3] = (short)f32_to_bf16(lo.w);
    r[4] = (short)f32_to_bf16(hi.x); r[5] = (short)f32_to_bf16(hi.y);
    r[6] = (short)f32_to_bf16(hi.z); r[7] = (short)f32_to_bf16(hi.w);
    return r;
}

__device__ __forceinline__ void gload16(const void* src, void* lds) {
    __builtin_amdgcn_global_load_lds(
        (const __attribute__((address_space(1))) void*)src,
        (__attribute__((address_space(3))) void*)lds, 16, 0, 0);
}

// ---------------- W pre-convert (FROZEN, passing) ----------------
__global__ __launch_bounds__(256)
void wconv_kernel(const float* __restrict__ Wq, const float* __restrict__ Wk,
                  const float* __restrict__ Wv, unsigned short* __restrict__ Wt)
{
    const int t  = blockIdx.x * 256 + threadIdx.x;
    const int n  = t & 127;
    const int kc = (t >> 7) & 127;
    const int p  = t >> 14;
    const float* __restrict__ W = (p == 0) ? Wq : (p == 1) ? Wk : Wv;
    const float sc = (p == 0) ? (1.44269504088896f * 0.0883883476483184f) : 1.0f;
    const float4* src = reinterpret_cast<const float4*>(W + (size_t)n * D_IN + kc * 8);
    float4 a = src[0], b = src[1];
    uint4 o;
    o.x = (uint32_t)f32_to_bf16(a.x * sc) | ((uint32_t)f32_to_bf16(a.y * sc) << 16);
    o.y = (uint32_t)f32_to_bf16(a.z * sc) | ((uint32_t)f32_to_bf16(a.w * sc) << 16);
    o.z = (uint32_t)f32_to_bf16(b.x * sc) | ((uint32_t)f32_to_bf16(b.y * sc) << 16);
    o.w = (uint32_t)f32_to_bf16(b.z * sc) | ((uint32_t)f32_to_bf16(b.w * sc) << 16);
    *reinterpret_cast<uint4*>(Wt + (size_t)t * 8) = o;
}

// ---------------- projection GEMM v14 (FROZEN, passing) --------------------
#define RBM 32

__global__ __launch_bounds__(256, 3)
void proj_kernel(const float* __restrict__ Xq, const float* __restrict__ Xk,
                 const float* __restrict__ Xv,
                 const unsigned short* __restrict__ Wt,
                 unsigned short* __restrict__ qh, unsigned short* __restrict__ kh,
                 unsigned short* __restrict__ vhT)
{
    const int p = blockIdx.y;
    const float* __restrict__ X = (p == 0) ? Xq : (p == 1) ? Xk : Xv;
    const unsigned short* __restrict__ Wtp = Wt + (size_t)p * 128 * 128 * 8;

    __shared__ float Asf[RBM * 256];   // 32KB [row][256 f32], 32B-XOR swizzled

    const int tid  = threadIdx.x;
    const int lane = tid & 63;
    const int w    = tid >> 6;           // wave = column group (32 cols)
    const int lrow = lane & 15;
    const int g    = lane >> 4;
    const int wbase = blockIdx.x * RBM;

    f32x4 acc[2][2];
    #pragma unroll
    for (int mi = 0; mi < 2; ++mi)
        #pragma unroll
        for (int ni = 0; ni < 2; ++ni)
            acc[mi][ni] = (f32x4){0.f, 0.f, 0.f, 0.f};

    char* const abase0 = reinterpret_cast<char*>(Asf) + lrow * 1024;
    char* const abase1 = reinterpret_cast<char*>(Asf) + (16 + lrow) * 1024;
    const int aswz = (lrow & 7) << 5;
    bf16x8 bb[8];

    #pragma unroll
    for (int kk = 0; kk < 4; ++kk) {
        if (kk) __syncthreads();

        const unsigned short* __restrict__ wbk =
            Wtp + ((size_t)(kk * 32 + g) * 128 + w * 32 + lrow) * 8;
        #pragma unroll
        for (int s = 0; s < 4; ++s)
            #pragma unroll
            for (int ni = 0; ni < 2; ++ni)
                bb[s * 2 + ni] = *reinterpret_cast<const bf16x8*>(
                    wbk + ((size_t)(s * 4) * 128 + ni * 16) * 8);

        {
            const int r0 = w * 8;
            const char* src = reinterpret_cast<const char*>(
                X + (size_t)(wbase + r0) * D_IN + kk * 256) + lane * 16;
            float4 L0 = *reinterpret_cast<const float4*>(src);
            float4 L1 = *reinterpret_cast<const float4*>(src + 1 * 4096);
            float4 L2 = *reinterpret_cast<const float4*>(src + 2 * 4096);
            float4 L3 = *reinterpret_cast<const float4*>(src + 3 * 4096);
            float4 L4 = *reinterpret_cast<const float4*>(src + 4 * 4096);
            float4 L5 = *reinterpret_cast<const float4*>(src + 5 * 4096);
            float4 L6 = *reinterpret_cast<const float4*>(src + 6 * 4096);
            float4 L7 = *reinterpret_cast<const float4*>(src + 7 * 4096);
            char* const dst = reinterpret_cast<char*>(Asf);
            const int lb = lane * 16;
            #define WR(i, Li)                                                  \
            do {                                                               \
                const int r_ = r0 + (i);                                       \
                *reinterpret_cast<float4*>(dst + r_ * 1024 +                   \
                    (lb ^ ((r_ & 7) << 5))) = Li;                              \
            } while (0)
            WR(0, L0); WR(1, L1); WR(2, L2); WR(3, L3);
            WR(4, L4); WR(5, L5); WR(6, L6); WR(7, L7);
            #undef WR
        }
        __syncthreads();

        #pragma unroll
        for (int bt = 0; bt < 2; ++bt) {
            #pragma unroll
            for (int s = 0; s < 4; ++s) {
                const int t = bt * 4 + s;
                const int boff = (t * 128 + g * 32) ^ aswz;
                float4 lo0 = *reinterpret_cast<const float4*>(abase0 + boff);
                float4 hi0 = *reinterpret_cast<const float4*>(abase0 + boff + 16);
                float4 lo1 = *reinterpret_cast<const float4*>(abase1 + boff);
                float4 hi1 = *reinterpret_cast<const float4*>(abase1 + boff + 16);
                bf16x8 af0 = cvt8(lo0, hi0);
                bf16x8 af1 = cvt8(lo1, hi1);
                acc[0][0] = __builtin_amdgcn_mfma_f32_16x16x32_bf16(af0, bb[s * 2 + 0], acc[0][0], 0, 0, 0);
                acc[0][1] = __builtin_amdgcn_mfma_f32_16x16x32_bf16(af0, bb[s * 2 + 1], acc[0][1], 0, 0, 0);
                acc[1][0] = __builtin_amdgcn_mfma_f32_16x16x32_bf16(af1, bb[s * 2 + 0], acc[1][0], 0, 0, 0);
                acc[1][1] = __builtin_amdgcn_mfma_f32_16x16x32_bf16(af1, bb[s * 2 + 1], acc[1][1], 0, 0, 0);
                if (bt == 0) {
                    #pragma unroll
                    for (int ni = 0; ni < 2; ++ni)
                        bb[s * 2 + ni] = *reinterpret_cast<const bf16x8*>(
                            wbk + ((size_t)(16 + s * 4) * 128 + ni * 16) * 8);
                }
            }
        }
    }

    if (p < 2) {
        unsigned short* __restrict__ Y = (p == 0) ? qh : kh;
        #pragma unroll
        for (int mi = 0; mi < 2; ++mi) {
            const int rbase = wbase + mi * 16 + g * 4;
            #pragma unroll
            for (int ni = 0; ni < 2; ++ni) {
                const int n = w * 32 + ni * 16 + lrow;
                #pragma unroll
                for (int r = 0; r < 4; ++r)
                    Y[(size_t)(rbase + r) * D_K + n] = f32_to_bf16(acc[mi][ni][r]);
            }
        }
    } else {
        const int b = wbase >> 12;
        #pragma unroll
        for (int mi = 0; mi < 2; ++mi) {
            const int s = (wbase & 4095) + mi * 16 + g * 4;
            #pragma unroll
            for (int ni = 0; ni < 2; ++ni) {
                const int d = w * 32 + ni * 16 + lrow;
                uint2 t;
                t.x = (uint32_t)f32_to_bf16(acc[mi][ni][0]) |
                      ((uint32_t)f32_to_bf16(acc[mi][ni][1]) << 16);
                t.y = (uint32_t)f32_to_bf16(acc[mi][ni][2]) |
                      ((uint32_t)f32_to_bf16(acc[mi][ni][3]) << 16);
                *reinterpret_cast<uint2*>(vhT + ((size_t)(b * D_K + d) << 12) + s) = t;
            }
        }
    }
}

// ---------------- flash attention v11: swapped QK^T + packed P -------------
// mfma(kf, qf) puts S[q=lrow][kv=16sf+4g+r] in-lane: P converts via
// v_cvt_pk_bf16_f32 (8 ops) + 4x ds_write_b64 into a [16][144B-stride]
// buffer (bank-spread, b128-aligned reads). Single-scalar lsum, end-reduced
// via shfl_xor(16/32); per-row inverse fetched by 4 end shfls.
#define KVB 64
#define PSTRIDE 144

__global__ __launch_bounds__(256, 2)
void attn_kernel(const unsigned short* __restrict__ qh,
                 const unsigned short* __restrict__ kh,
                 const unsigned short* __restrict__ vhT,
                 float* __restrict__ out)
{
    __shared__ unsigned short Ks[2][KVB * D_K];   // 2 x 16KB
    __shared__ unsigned short Vs[2][D_K * KVB];   // 2 x 16KB (V^T)
    __shared__ char Ps[4][16 * PSTRIDE];          // per-wave [16 rows][144B]

    const int tid  = threadIdx.x;
    const int lane = tid & 63;
    const int wave = tid >> 6;
    const int b    = blockIdx.x & 7;     // batch -> XCD L2 locality
    const int qt   = blockIdx.x >> 3;
    const int q0   = qt * 64 + wave * 16;
    const int lrow = lane & 15;
    const int g    = lane >> 4;
    const int g4   = g << 2;
    const int lk16 = g * 16;

    const unsigned short* __restrict__ Kb = kh + (size_t)b * SEQ * D_K;
    const unsigned short* __restrict__ Vb = vhT + (size_t)b * D_K * SEQ;
    char* const Pw = Ps[wave];

    const int kr0  = lane >> 4;
    const int kcbp = (lane & 15) * 16;
    const int vr0  = lane >> 3;
    const int vcbp = (lane & 7) * 16;

    #define STAGE(buf, it_)                                                   \
    do {                                                                      \
        const int s0_ = (it_) * KVB;                                          \
        _Pragma("unroll")                                                     \
        for (int j = 0; j < 4; ++j) {                                         \
            const int blk  = wave * 4 + j;                                    \
            const int krow = blk * 4 + kr0;                                   \
            gload16(reinterpret_cast<const char*>(Kb) +                       \
                        (size_t)(s0_ + krow) * 256 +                          \
                        (kcbp ^ ((krow & 7) << 4)),                           \
                    reinterpret_cast<char*>(Ks[buf]) + blk * 1024);           \
            const int vrow = blk * 8 + vr0;                                   \
            gload16(reinterpret_cast<const char*>(Vb) +                       \
                        (size_t)vrow * (SEQ * 2) + (size_t)s0_ * 2 +          \
                        (vcbp ^ ((vrow & 7) << 4)),                           \
                    reinterpret_cast<char*>(Vs[buf]) + blk * 1024);           \
        }                                                                     \
    } while (0)

    // hoisted Q fragments (16 rows per wave, scaled by log2e/sqrt(128))
    bf16x8 qf[4];
    {
        const char* base = reinterpret_cast<const char*>(
            qh + (size_t)(b * SEQ + q0 + lrow) * D_K);
        #pragma unroll
        for (int ks = 0; ks < 4; ++ks)
            qf[ks] = *reinterpret_cast<const bf16x8*>(base + ks * 64 + lk16);
    }

    f32x4 o[8];
    #pragma unroll
    for (int df = 0; df < 8; ++df) o[df] = (f32x4){0.f, 0.f, 0.f, 0.f};
    float lsum = 0.f;

    STAGE(0, 0);
    asm volatile("s_waitcnt vmcnt(0)" ::: "memory");
    __syncthreads();

    int cur = 0;
    for (int it = 0; it < SEQ / KVB; ++it) {
        if (it + 1 < SEQ / KVB) STAGE(cur ^ 1, it + 1);

        // QK^T swapped: scT[sf][r] = S[q=lrow][kv = sf*16 + 4g + r]
        f32x4 scT[4];
        #pragma unroll
        for (int sf = 0; sf < 4; ++sf) scT[sf] = (f32x4){0.f, 0.f, 0.f, 0.f};
        #pragma unroll
        for (int ks = 0; ks < 4; ++ks) {
            #pragma unroll
            for (int sf = 0; sf < 4; ++sf) {
                const int row = sf * 16 + lrow;
                bf16x8 kf = *reinterpret_cast<const bf16x8*>(
                    reinterpret_cast<const char*>(Ks[cur]) + row * 256 +
                    ((ks * 64 + lk16) ^ ((row & 7) << 4)));
                scT[sf] = __builtin_amdgcn_mfma_f32_16x16x32_bf16(kf, qf[ks], scT[sf], 0, 0, 0);
            }
        }

        // softmax numerators: 16 exp2, pack to bf16 pairs, 4x ds_write_b64.
        // P[lrow][kv=16sf+4g..+3] -> bytes lrow*144 + (4sf+g)*8 (kv-linear).
        #pragma unroll
        for (int sf = 0; sf < 4; ++sf) {
            float p0 = exp2f(scT[sf][0]);
            float p1 = exp2f(scT[sf][1]);
            float p2 = exp2f(scT[sf][2]);
            float p3 = exp2f(scT[sf][3]);
            lsum += (p0 + p1) + (p2 + p3);
            uint32_t u0, u1;
            asm("v_cvt_pk_bf16_f32 %0, %1, %2" : "=v"(u0) : "v"(p0), "v"(p1));
            asm("v_cvt_pk_bf16_f32 %0, %1, %2" : "=v"(u1) : "v"(p2), "v"(p3));
            uint2 t; t.x = u0; t.y = u1;
            *reinterpret_cast<uint2*>(Pw + lrow * PSTRIDE + (4 * sf + g) * 8) = t;
        }

        // PV: pf[ks2] = P[lrow][32ks2+8g .. +7] (b128, 16B-aligned: 144=9*16)
        #pragma unroll
        for (int ks = 0; ks < 2; ++ks) {
            bf16x8 pf = *reinterpret_cast<const bf16x8*>(
                Pw + lrow * PSTRIDE + ks * 64 + g * 16);
            #pragma unroll
            for (int df = 0; df < 8; ++df) {
                const int vr = df * 16 + lrow;
                bf16x8 vf = *reinterpret_cast<const bf16x8*>(
                    reinterpret_cast<const char*>(Vs[cur]) + vr * 128 +
                    ((ks * 64 + lk16) ^ ((vr & 7) << 4)));
                o[df] = __builtin_amdgcn_mfma_f32_16x16x32_bf16(pf, vf, o[df], 0, 0, 0);
            }
        }

        asm volatile("s_waitcnt vmcnt(0)" ::: "memory");
        __syncthreads();
        cur ^= 1;
    }
    #undef STAGE

    // row-sum: lane holds partial of row lrow; combine across the 4 g-copies
    float s = lsum;
    s += __shfl_xor(s, 16);
    s += __shfl_xor(s, 32);
    // o rows are g4+r -> fetch that row's sum from lane (g4+r)
    #pragma unroll
    for (int r = 0; r < 4; ++r) {
        float inv = 1.0f / __shfl(s, g4 + r);
        const int row = q0 + g4 + r;
        float* ob = out + (size_t)(b * SEQ + row) * D_K + lrow;
        #pragma unroll
        for (int df = 0; df < 8; ++df)
            ob[df * 16] = o[df][r] * inv;
    }
}

extern "C" void kernel_launch(void* const* d_in, const int* in_sizes, int n_in,
                              void* d_out, int out_size, void* d_ws, size_t ws_size,
                              hipStream_t stream)
{
    (void)in_sizes; (void)n_in; (void)out_size; (void)ws_size;
    const float* q  = (const float*)d_in[0];
    const float* k  = (const float*)d_in[1];
    const float* v  = (const float*)d_in[2];
    const float* Wq = (const float*)d_in[3];
    const float* Wk = (const float*)d_in[4];
    const float* Wv = (const float*)d_in[5];

    unsigned short* qh  = (unsigned short*)d_ws;                 // [32768][128] bf16
    unsigned short* kh  = qh + (size_t)MROWS * D_K;              // [32768][128] bf16
    unsigned short* vhT = kh + (size_t)MROWS * D_K;              // [8][128][4096] bf16
    unsigned short* Wt  = vhT + (size_t)MROWS * D_K;             // [3][128][128][8] bf16

    wconv_kernel<<<dim3(192), 256, 0, stream>>>(Wq, Wk, Wv, Wt);
    proj_kernel<<<dim3(MROWS / RBM, 3), 256, 0, stream>>>(q, k, v, Wt, qh, kh, vhT);
    attn_kernel<<<dim3(NBATCH * (SEQ / 64)), 256, 0, stream>>>(qh, kh, vhT, (float*)d_out);
}